// Round 5
// baseline (109.185 us; speedup 1.0000x reference)
//
#include <hip/hip_runtime.h>
#include <hip/hip_bf16.h>

#define BB 8192
#define TT 50
#define II 50
#define HH 10
#define CC 5

typedef __attribute__((ext_vector_type(8))) short short8;
typedef __attribute__((ext_vector_type(4))) float f32x4;

__device__ __forceinline__ float fast_tanh(float x) {
    float e = __expf(2.0f * x);
    return 1.0f - 2.0f * __builtin_amdgcn_rcpf(e + 1.0f);
}
__device__ __forceinline__ unsigned short bfbits(float f) {
    __hip_bfloat16 h = __float2bfloat16(f);
    union { __hip_bfloat16 h; unsigned short u; } cv;
    cv.h = h;
    return cv.u;
}
__device__ __forceinline__ unsigned int packbf(float a, float b) {
    return ((unsigned int)bfbits(b) << 16) | (unsigned int)bfbits(a);
}

// After calling with u=v=x: {u,v} = {x_self, x_partner} across the xor-16 / xor-32
// lane split (order HW-defined; only used for commutative sums here).
__device__ __forceinline__ void swap16(float& u, float& v) {
#if __has_builtin(__builtin_amdgcn_permlane16_swap)
    auto r = __builtin_amdgcn_permlane16_swap(__float_as_uint(u), __float_as_uint(v), false, false);
    u = __uint_as_float(r[0]);
    v = __uint_as_float(r[1]);
#else
    asm("s_nop 1\n\tv_permlane16_swap_b32 %0, %1\n\ts_nop 0" : "+v"(u), "+v"(v));
#endif
}
__device__ __forceinline__ void swap32(float& u, float& v) {
#if __has_builtin(__builtin_amdgcn_permlane32_swap)
    auto r = __builtin_amdgcn_permlane32_swap(__float_as_uint(u), __float_as_uint(v), false, false);
    u = __uint_as_float(r[0]);
    v = __uint_as_float(r[1]);
#else
    asm("s_nop 1\n\tv_permlane32_swap_b32 %0, %1\n\ts_nop 0" : "+v"(u), "+v"(v));
#endif
}

// K1: P[t][j][b] = sum_i x[b][t][i] * Wih0[j][i] + (bih0[j]+bhh0[j])
__global__ __launch_bounds__(256) void k_proj0(
    const float* __restrict__ x, const float* __restrict__ Wih0,
    const float* __restrict__ bih0, const float* __restrict__ bhh0,
    float* __restrict__ P) {
    int gid = blockIdx.x * 256 + threadIdx.x;   // 0 .. B*T-1
    int b = gid & (BB - 1);
    int t = gid >> 13;                          // B = 2^13
    const float2* xr = (const float2*)(x + ((size_t)b * TT + t) * II);
    float2 xv[II / 2];
#pragma unroll
    for (int i = 0; i < II / 2; i++) xv[i] = xr[i];
#pragma unroll
    for (int j = 0; j < HH; j++) {
        float a = bih0[j] + bhh0[j];
        const float2* w = (const float2*)(Wih0 + j * II);
#pragma unroll
        for (int i = 0; i < II / 2; i++) {
            float2 wv = w[i];
            a = fmaf(wv.x, xv[i].x, a);
            a = fmaf(wv.y, xv[i].y, a);
        }
        P[((size_t)t * HH + j) * BB + b] = a;
    }
}

// K2: fused 3-layer recurrence + FC via MFMA. One wave = 16 batches.
// Per layer per step: D[j][b] = mfma_16x16x32_bf16(A=W, B=h_lds, C=P/bias).
// LDS region per (layer,batch): 64 B = bf16 k-vector for the B operand:
//   L0: [h_own(k0-9) | zeros]
//   L1/L2: [h_prev_layer(k0-9) | zero k10-11 | h_own(k12-21) | zeros]
// A frags built with the SAME (group,elem)->k map -> layout-map cancels.
// Single wave per block -> DS ops in-order, no barriers needed.
__global__ __launch_bounds__(64, 1) void k_fused(
    const float* __restrict__ h0all,
    const float* __restrict__ Whh0,
    const float* __restrict__ Wih1, const float* __restrict__ Whh1,
    const float* __restrict__ bih1, const float* __restrict__ bhh1,
    const float* __restrict__ Wih2, const float* __restrict__ Whh2,
    const float* __restrict__ bih2, const float* __restrict__ bhh2,
    const float* __restrict__ fcw, const float* __restrict__ fcb,
    const float* __restrict__ P, float* __restrict__ out) {
    __shared__ __align__(16) char regA[3 * 16 * 64];   // [layer][b_loc][64 B]
    __shared__ __align__(16) float sfc[TT * CC * 16];  // fcw packed by j-row, 16 KB

    const int lane = threadIdx.x;
    const int bl = lane & 15;    // batch within wave (MFMA col = lane&15)
    const int g = lane >> 4;     // lane group (k-slice for A/B, j-row-group for C/D)
    const int bb0 = blockIdx.x * 16;
    const int b = bb0 + bl;

    // ---- init LDS ----
    for (int i = lane; i < 3 * 16 * 16; i += 64) ((unsigned int*)regA)[i] = 0u;
    for (int i = lane; i < TT * CC * 16; i += 64) {
        int jj = i & 15;
        int rc = i >> 4;
        int c = rc % CC;
        int t = rc / CC;
        sfc[i] = (jj < HH) ? fcw[(size_t)c * (TT * HH) + t * HH + jj] : 0.0f;
    }
    // h0 -> regions (L0 own at bytes 0..19; L1/L2 own at bytes 24..43)
    for (int i = lane; i < 240; i += 64) {
        int layer = i / 80;
        int r = i % 80;
        int bb = r / 5;
        int pr = r % 5;
        const float* src = h0all + (size_t)layer * BB * HH + (size_t)(bb0 + bb) * HH + pr * 2;
        unsigned int pk = packbf(src[0], src[1]);
        *(unsigned int*)(regA + layer * 1024 + bb * 64 + (layer ? 24 : 0) + pr * 4) = pk;
    }

    // ---- A fragments (per-lane: row m = lane&15, k = g*8+e) ----
    short8 A0, A1, A2;
    const int m = bl;
#pragma unroll
    for (int e = 0; e < 8; e++) {
        int kv = g * 8 + e;
        float v0 = 0.0f, v1 = 0.0f, v2 = 0.0f;
        if (m < HH) {
            if (kv < HH) {
                v0 = Whh0[m * HH + kv];
                v1 = Wih1[m * HH + kv];
                v2 = Wih2[m * HH + kv];
            } else if (kv >= 12 && kv < 12 + HH) {
                v1 = Whh1[m * HH + (kv - 12)];
                v2 = Whh2[m * HH + (kv - 12)];
            }
        }
        A0[e] = (short)bfbits(v0);
        A1[e] = (short)bfbits(v1);
        A2[e] = (short)bfbits(v2);
    }
    // bias C-fragments (row j = g*4+r)
    f32x4 bC1, bC2;
#pragma unroll
    for (int r = 0; r < 4; r++) {
        int j = g * 4 + r;
        bC1[r] = (j < HH) ? (bih1[j] + bhh1[j]) : 0.0f;
        bC2[r] = (j < HH) ? (bih2[j] + bhh2[j]) : 0.0f;
    }

    float acc[CC] = {0.0f, 0.0f, 0.0f, 0.0f, 0.0f};

    // first P fragment (C layout: row j = g*4+r, col b)
    f32x4 pcur;
#pragma unroll
    for (int r = 0; r < 4; r++) {
        int j = g * 4 + r;
        pcur[r] = (j < HH) ? P[((size_t)0 * HH + j) * BB + b] : 0.0f;
    }

    char* r0 = regA + bl * 64;
    char* r1 = regA + 1024 + bl * 64;
    char* r2 = regA + 2048 + bl * 64;

#pragma unroll 1
    for (int t = 0; t < TT; t++) {
        short8 B0 = *(const short8*)(r0 + g * 16);
        f32x4 fcv[CC];
#pragma unroll
        for (int c = 0; c < CC; c++)
            fcv[c] = *(const f32x4*)&sfc[(t * CC + c) * 16 + g * 4];
        f32x4 pn = {0.0f, 0.0f, 0.0f, 0.0f};
        if (t + 1 < TT) {
#pragma unroll
            for (int r = 0; r < 4; r++) {
                int j = g * 4 + r;
                if (j < HH) pn[r] = P[((size_t)(t + 1) * HH + j) * BB + b];
            }
        }
        // ---- layer 0 ----
        f32x4 D0 = __builtin_amdgcn_mfma_f32_16x16x32_bf16(A0, B0, pcur, 0, 0, 0);
        float th[4];
#pragma unroll
        for (int r = 0; r < 4; r++) th[r] = fast_tanh(D0[r]);
        unsigned int p01 = packbf(th[0], th[1]);
        unsigned int p23 = packbf(th[2], th[3]);
        if (g < 2) {
            uint2 w; w.x = p01; w.y = p23;
            *(uint2*)(r0 + g * 8) = w;       // own (next step)
            *(uint2*)(r1 + g * 8) = w;       // prev for L1 (this step)
        } else if (g == 2) {
            *(unsigned int*)(r0 + 16) = p01;
            *(unsigned int*)(r1 + 16) = p01;
        }
        // ---- layer 1 ----
        short8 B1 = *(const short8*)(r1 + g * 16);
        f32x4 D1 = __builtin_amdgcn_mfma_f32_16x16x32_bf16(A1, B1, bC1, 0, 0, 0);
#pragma unroll
        for (int r = 0; r < 4; r++) th[r] = fast_tanh(D1[r]);
        p01 = packbf(th[0], th[1]);
        p23 = packbf(th[2], th[3]);
        if (g < 2) {
            uint2 w; w.x = p01; w.y = p23;
            *(uint2*)(r1 + 24 + g * 8) = w;  // own (next step)
            *(uint2*)(r2 + g * 8) = w;       // prev for L2 (this step)
        } else if (g == 2) {
            *(unsigned int*)(r1 + 40) = p01;
            *(unsigned int*)(r2 + 16) = p01;
        }
        // ---- layer 2 ----
        short8 B2 = *(const short8*)(r2 + g * 16);
        f32x4 D2 = __builtin_amdgcn_mfma_f32_16x16x32_bf16(A2, B2, bC2, 0, 0, 0);
#pragma unroll
        for (int r = 0; r < 4; r++) th[r] = fast_tanh(D2[r]);
        // FC partial (f32 h2, full precision)
        float rl[4];
#pragma unroll
        for (int r = 0; r < 4; r++) rl[r] = fmaxf(th[r], 0.0f);
#pragma unroll
        for (int c = 0; c < CC; c++) {
#pragma unroll
            for (int r = 0; r < 4; r++) acc[c] = fmaf(fcv[c][r], rl[r], acc[c]);
        }
        p01 = packbf(th[0], th[1]);
        p23 = packbf(th[2], th[3]);
        if (g < 2) {
            uint2 w; w.x = p01; w.y = p23;
            *(uint2*)(r2 + 24 + g * 8) = w;  // own (next step)
        } else if (g == 2) {
            *(unsigned int*)(r2 + 40) = p01;
        }
        pcur = pn;
    }

    // reduce acc across the 4 lane groups (commutative sums, orientation-immune)
#pragma unroll
    for (int c = 0; c < CC; c++) {
        float u = acc[c], v = acc[c];
        swap16(u, v);
        float s = u + v;
        float u2 = s, v2 = s;
        swap32(u2, v2);
        acc[c] = u2 + v2 + fcb[c];
    }
    if (g == 0) {
#pragma unroll
        for (int c = 0; c < CC; c++) out[(size_t)b * CC + c] = acc[c];
    }
}

extern "C" void kernel_launch(void* const* d_in, const int* in_sizes, int n_in,
                              void* d_out, int out_size, void* d_ws, size_t ws_size,
                              hipStream_t stream) {
    const float* x    = (const float*)d_in[0];
    const float* h0   = (const float*)d_in[1];
    const float* Wih0 = (const float*)d_in[2];
    const float* Whh0 = (const float*)d_in[3];
    const float* bih0 = (const float*)d_in[4];
    const float* bhh0 = (const float*)d_in[5];
    const float* Wih1 = (const float*)d_in[6];
    const float* Whh1 = (const float*)d_in[7];
    const float* bih1 = (const float*)d_in[8];
    const float* bhh1 = (const float*)d_in[9];
    const float* Wih2 = (const float*)d_in[10];
    const float* Whh2 = (const float*)d_in[11];
    const float* bih2 = (const float*)d_in[12];
    const float* bhh2 = (const float*)d_in[13];
    const float* fcw  = (const float*)d_in[14];
    const float* fcb  = (const float*)d_in[15];
    float* out = (float*)d_out;
    float* P   = (float*)d_ws;   // [T][H][B] = 16.38 MB

    k_proj0<<<(BB * TT) / 256, 256, 0, stream>>>(x, Wih0, bih0, bhh0, P);
    k_fused<<<BB / 16, 64, 0, stream>>>(h0, Whh0, Wih1, Whh1, bih1, bhh1,
                                        Wih2, Whh2, bih2, bhh2, fcw, fcb, P, out);
}

// Round 6
// 106.934 us; speedup vs baseline: 1.0211x; 1.0211x over previous
//
#include <hip/hip_runtime.h>
#include <hip/hip_bf16.h>

#define BB 8192
#define TT 50
#define II 50
#define HH 10
#define CC 5

typedef __attribute__((ext_vector_type(8))) short short8;
typedef __attribute__((ext_vector_type(4))) float f32x4;

struct U4 { unsigned x, y, z, w; };
__device__ __forceinline__ short8 toB(unsigned a, unsigned b, unsigned c, unsigned d) {
    U4 u{a, b, c, d};
    return __builtin_bit_cast(short8, u);
}

__device__ __forceinline__ float fast_tanh(float x) {
    float e = __expf(2.0f * x);
    return 1.0f - 2.0f * __builtin_amdgcn_rcpf(e + 1.0f);
}
__device__ __forceinline__ unsigned short bfbits(float f) {
    __hip_bfloat16 h = __float2bfloat16(f);
    union { __hip_bfloat16 h; unsigned short u; } cv;
    cv.h = h;
    return cv.u;
}
__device__ __forceinline__ unsigned packbf(float a, float b) {
    return ((unsigned)bfbits(b) << 16) | (unsigned)bfbits(a);
}

// {u,v} <- {x@(g pair-even), x@(g pair-odd)} across xor-16 / xor-32 lane split.
// Order is HW-defined; resolved at runtime via probe flags f16lo/f32lo.
__device__ __forceinline__ void uswap16(unsigned& u, unsigned& v) {
#if __has_builtin(__builtin_amdgcn_permlane16_swap)
    auto r = __builtin_amdgcn_permlane16_swap(u, v, false, false);
    u = r[0]; v = r[1];
#else
    asm("s_nop 1\n\tv_permlane16_swap_b32 %0, %1\n\ts_nop 0" : "+v"(u), "+v"(v));
#endif
}
__device__ __forceinline__ void uswap32(unsigned& u, unsigned& v) {
#if __has_builtin(__builtin_amdgcn_permlane32_swap)
    auto r = __builtin_amdgcn_permlane32_swap(u, v, false, false);
    u = r[0]; v = r[1];
#else
    asm("s_nop 1\n\tv_permlane32_swap_b32 %0, %1\n\ts_nop 0" : "+v"(u), "+v"(v));
#endif
}
__device__ __forceinline__ void fswap16(float& u, float& v) {
    unsigned a = __float_as_uint(u), b = __float_as_uint(v);
    uswap16(a, b);
    u = __uint_as_float(a); v = __uint_as_float(b);
}
__device__ __forceinline__ void fswap32(float& u, float& v) {
    unsigned a = __float_as_uint(u), b = __float_as_uint(v);
    uswap32(a, b);
    u = __uint_as_float(a); v = __uint_as_float(b);
}

// Broadcast the 5 packed row-dwords of one h-vector (rows 01,23,45,67,89) from
// their home lane-groups to ALL lanes. a = pack(row 4g, 4g+1), b = pack(4g+2, 4g+3).
struct BC { unsigned a0, a1, a2, b0, b1; };  // aK = pack(rows 8K?No: a0=r01,a1=r45,a2=r89,b0=r23,b1=r67)
__device__ __forceinline__ BC broadcast5(unsigned a, unsigned bq, bool f16lo, bool f32lo) {
    BC r;
    unsigned u, v;
    u = a; v = a; uswap16(u, v);
    unsigned alo = f16lo ? u : v, ahi = f16lo ? v : u;   // a@(g&~1), a@(g|1)
    u = alo; v = alo; uswap32(u, v);
    r.a0 = f32lo ? u : v;                                // a@G0 = rows 0,1
    r.a2 = f32lo ? v : u;                                // a@G2 = rows 8,9
    u = ahi; v = ahi; uswap32(u, v);
    r.a1 = f32lo ? u : v;                                // a@G1 = rows 4,5
    u = bq; v = bq; uswap16(u, v);
    unsigned blo = f16lo ? u : v, bhi = f16lo ? v : u;
    u = blo; v = blo; uswap32(u, v);
    r.b0 = f32lo ? u : v;                                // b@G0 = rows 2,3
    u = bhi; v = bhi; uswap32(u, v);
    r.b1 = f32lo ? u : v;                                // b@G1 = rows 6,7
    return r;
}

// K1: P[t][j][b] = sum_i x[b][t][i] * Wih0[j][i] + (bih0[j]+bhh0[j])
__global__ __launch_bounds__(256) void k_proj0(
    const float* __restrict__ x, const float* __restrict__ Wih0,
    const float* __restrict__ bih0, const float* __restrict__ bhh0,
    float* __restrict__ P) {
    int gid = blockIdx.x * 256 + threadIdx.x;
    int b = gid & (BB - 1);
    int t = gid >> 13;
    const float2* xr = (const float2*)(x + ((size_t)b * TT + t) * II);
    float2 xv[II / 2];
#pragma unroll
    for (int i = 0; i < II / 2; i++) xv[i] = xr[i];
#pragma unroll
    for (int j = 0; j < HH; j++) {
        float a = bih0[j] + bhh0[j];
        const float2* w = (const float2*)(Wih0 + j * II);
#pragma unroll
        for (int i = 0; i < II / 2; i++) {
            float2 wv = w[i];
            a = fmaf(wv.x, xv[i].x, a);
            a = fmaf(wv.y, xv[i].y, a);
        }
        P[((size_t)t * HH + j) * BB + b] = a;
    }
}

// K2: fused 3-layer recurrence + FC via MFMA, D->B via permlane (no LDS in loop).
// One wave = 16 batches. B-vector k-map (verified by round-5 pass):
//   L0: k0-9 = h0 rows 0-9;  L1/L2: k0-9 = prev-layer h rows 0-9, k12-21 = own h rows 0-9.
// Lane (g,bl): B-frag dword d = k pair (g*8+2d, g*8+2d+1), col = bl.
__global__ __launch_bounds__(64, 1) void k_fused(
    const float* __restrict__ h0all,
    const float* __restrict__ Whh0,
    const float* __restrict__ Wih1, const float* __restrict__ Whh1,
    const float* __restrict__ bih1, const float* __restrict__ bhh1,
    const float* __restrict__ Wih2, const float* __restrict__ Whh2,
    const float* __restrict__ bih2, const float* __restrict__ bhh2,
    const float* __restrict__ fcw, const float* __restrict__ fcb,
    const float* __restrict__ P, float* __restrict__ out) {
    __shared__ __align__(16) float sfc[TT * CC * 16];  // fcw packed by j-row, 16 KB

    const int lane = threadIdx.x;
    const int bl = lane & 15;
    const int g = lane >> 4;
    const int b = blockIdx.x * 16 + bl;

    for (int i = lane; i < TT * CC * 16; i += 64) {
        int jj = i & 15;
        int rc = i >> 4;
        int c = rc % CC;
        int t = rc / CC;
        sfc[i] = (jj < HH) ? fcw[(size_t)c * (TT * HH) + t * HH + jj] : 0.0f;
    }

    // ---- orientation probes (2 swaps, integer-exact compares) ----
    unsigned pu, pv;
    pu = pv = (unsigned)g; uswap16(pu, pv);
    const bool f16lo = (pu == (unsigned)(g & ~1));
    pu = pv = (unsigned)g; uswap32(pu, pv);
    const bool f32lo = (pu == (unsigned)(g & ~2));

    const bool g0 = (g == 0), g1 = (g == 1), g2 = (g == 2);

    // ---- A fragments (row m = bl, k = g*8+e) — identical to verified round 5 ----
    short8 A0, A1, A2;
    const int m = bl;
#pragma unroll
    for (int e = 0; e < 8; e++) {
        int kv = g * 8 + e;
        float v0 = 0.0f, v1 = 0.0f, v2 = 0.0f;
        if (m < HH) {
            if (kv < HH) {
                v0 = Whh0[m * HH + kv];
                v1 = Wih1[m * HH + kv];
                v2 = Wih2[m * HH + kv];
            } else if (kv >= 12 && kv < 12 + HH) {
                v1 = Whh1[m * HH + (kv - 12)];
                v2 = Whh2[m * HH + (kv - 12)];
            }
        }
        A0[e] = (short)bfbits(v0);
        A1[e] = (short)bfbits(v1);
        A2[e] = (short)bfbits(v2);
    }
    // bias C-fragments (row j = g*4+r)
    f32x4 bC1, bC2;
#pragma unroll
    for (int r = 0; r < 4; r++) {
        int j = g * 4 + r;
        bC1[r] = (j < HH) ? (bih1[j] + bhh1[j]) : 0.0f;
        bC2[r] = (j < HH) ? (bih2[j] + bhh2[j]) : 0.0f;
    }

    // ---- initial h state: every lane holds all 10 rows packed as 5 dwords ----
    unsigned h1a0, h1b0, h1a1, h1b1, h1a2;   // layer-1 own h (rows 01,23,45,67,89)
    unsigned h2a0, h2b0, h2a1, h2b1, h2a2;   // layer-2 own h
    short8 B0cur;
    {
        const float* s0 = h0all + (size_t)b * HH;
        const float* s1 = h0all + ((size_t)BB + b) * HH;
        const float* s2 = h0all + ((size_t)2 * BB + b) * HH;
        unsigned h0p[5];
#pragma unroll
        for (int r = 0; r < 5; r++) h0p[r] = packbf(s0[2 * r], s0[2 * r + 1]);
        h1a0 = packbf(s1[0], s1[1]); h1b0 = packbf(s1[2], s1[3]);
        h1a1 = packbf(s1[4], s1[5]); h1b1 = packbf(s1[6], s1[7]);
        h1a2 = packbf(s1[8], s1[9]);
        h2a0 = packbf(s2[0], s2[1]); h2b0 = packbf(s2[2], s2[3]);
        h2a1 = packbf(s2[4], s2[5]); h2b1 = packbf(s2[6], s2[7]);
        h2a2 = packbf(s2[8], s2[9]);
        // L0 B frag: g0: {a0,b0,a1,b1}; g1: {a2,0,0,0}; else 0
        B0cur = toB(g0 ? h0p[0] : (g1 ? h0p[4] : 0u),
                    g0 ? h0p[1] : 0u,
                    g0 ? h0p[2] : 0u,
                    g0 ? h0p[3] : 0u);
    }

    float acc[CC] = {0.0f, 0.0f, 0.0f, 0.0f, 0.0f};

    f32x4 pcur;
#pragma unroll
    for (int r = 0; r < 4; r++) {
        int j = g * 4 + r;
        pcur[r] = (j < HH) ? P[((size_t)0 * HH + j) * BB + b] : 0.0f;
    }

#pragma unroll 1
    for (int t = 0; t < TT; t++) {
        f32x4 fcv[CC];
#pragma unroll
        for (int c = 0; c < CC; c++)
            fcv[c] = *(const f32x4*)&sfc[(t * CC + c) * 16 + g * 4];
        f32x4 pn = {0.0f, 0.0f, 0.0f, 0.0f};
        if (t + 1 < TT) {
#pragma unroll
            for (int r = 0; r < 4; r++) {
                int j = g * 4 + r;
                if (j < HH) pn[r] = P[((size_t)(t + 1) * HH + j) * BB + b];
            }
        }
        float th[4];
        // ======== layer 0 ========
        f32x4 D0 = __builtin_amdgcn_mfma_f32_16x16x32_bf16(A0, B0cur, pcur, 0, 0, 0);
#pragma unroll
        for (int r = 0; r < 4; r++) th[r] = fast_tanh(D0[r]);
        BC p0 = broadcast5(packbf(th[0], th[1]), packbf(th[2], th[3]), f16lo, f32lo);
        // next-step L0 B frag
        short8 B0next = toB(g0 ? p0.a0 : (g1 ? p0.a2 : 0u),
                            g0 ? p0.b0 : 0u,
                            g0 ? p0.a1 : 0u,
                            g0 ? p0.b1 : 0u);
        // this-step L1 B frag: prev = p0 (k0-9), own = h1* (k12-21)
        short8 B1 = toB(g0 ? p0.a0 : (g1 ? p0.a2 : (g2 ? h1a1 : 0u)),
                        g0 ? p0.b0 : (g2 ? h1b1 : 0u),
                        g0 ? p0.a1 : (g1 ? h1a0 : (g2 ? h1a2 : 0u)),
                        g0 ? p0.b1 : (g1 ? h1b0 : 0u));
        // ======== layer 1 ========
        f32x4 D1 = __builtin_amdgcn_mfma_f32_16x16x32_bf16(A1, B1, bC1, 0, 0, 0);
#pragma unroll
        for (int r = 0; r < 4; r++) th[r] = fast_tanh(D1[r]);
        BC p1 = broadcast5(packbf(th[0], th[1]), packbf(th[2], th[3]), f16lo, f32lo);
        short8 B2 = toB(g0 ? p1.a0 : (g1 ? p1.a2 : (g2 ? h2a1 : 0u)),
                        g0 ? p1.b0 : (g2 ? h2b1 : 0u),
                        g0 ? p1.a1 : (g1 ? h2a0 : (g2 ? h2a2 : 0u)),
                        g0 ? p1.b1 : (g1 ? h2b0 : 0u));
        h1a0 = p1.a0; h1b0 = p1.b0; h1a1 = p1.a1; h1b1 = p1.b1; h1a2 = p1.a2;
        // ======== layer 2 ========
        f32x4 D2 = __builtin_amdgcn_mfma_f32_16x16x32_bf16(A2, B2, bC2, 0, 0, 0);
#pragma unroll
        for (int r = 0; r < 4; r++) th[r] = fast_tanh(D2[r]);
        // FC partial on own rows (f32, full precision)
#pragma unroll
        for (int c = 0; c < CC; c++) {
#pragma unroll
            for (int r = 0; r < 4; r++) acc[c] = fmaf(fcv[c][r], fmaxf(th[r], 0.0f), acc[c]);
        }
        BC p2 = broadcast5(packbf(th[0], th[1]), packbf(th[2], th[3]), f16lo, f32lo);
        h2a0 = p2.a0; h2b0 = p2.b0; h2a1 = p2.a1; h2b1 = p2.b1; h2a2 = p2.a2;

        B0cur = B0next;
        pcur = pn;
    }

    // reduce acc across the 4 lane groups (commutative sums, orientation-immune)
#pragma unroll
    for (int c = 0; c < CC; c++) {
        float u = acc[c], v = acc[c];
        fswap16(u, v);
        float s = u + v;
        float u2 = s, v2 = s;
        fswap32(u2, v2);
        acc[c] = u2 + v2 + fcb[c];
    }
    if (g == 0) {
#pragma unroll
        for (int c = 0; c < CC; c++) out[(size_t)b * CC + c] = acc[c];
    }
}

extern "C" void kernel_launch(void* const* d_in, const int* in_sizes, int n_in,
                              void* d_out, int out_size, void* d_ws, size_t ws_size,
                              hipStream_t stream) {
    const float* x    = (const float*)d_in[0];
    const float* h0   = (const float*)d_in[1];
    const float* Wih0 = (const float*)d_in[2];
    const float* Whh0 = (const float*)d_in[3];
    const float* bih0 = (const float*)d_in[4];
    const float* bhh0 = (const float*)d_in[5];
    const float* Wih1 = (const float*)d_in[6];
    const float* Whh1 = (const float*)d_in[7];
    const float* bih1 = (const float*)d_in[8];
    const float* bhh1 = (const float*)d_in[9];
    const float* Wih2 = (const float*)d_in[10];
    const float* Whh2 = (const float*)d_in[11];
    const float* bih2 = (const float*)d_in[12];
    const float* bhh2 = (const float*)d_in[13];
    const float* fcw  = (const float*)d_in[14];
    const float* fcb  = (const float*)d_in[15];
    float* out = (float*)d_out;
    float* P   = (float*)d_ws;   // [T][H][B] = 16.38 MB

    k_proj0<<<(BB * TT) / 256, 256, 0, stream>>>(x, Wih0, bih0, bhh0, P);
    k_fused<<<BB / 16, 64, 0, stream>>>(h0, Whh0, Wih1, Whh1, bih1, bhh1,
                                        Wih2, Whh2, bih2, bhh2, fcw, fcb, P, out);
}

// Round 7
// 85.427 us; speedup vs baseline: 1.2781x; 1.2518x over previous
//
#include <hip/hip_runtime.h>
#include <hip/hip_bf16.h>

#define BB 8192
#define TT 50
#define II 50
#define HH 10
#define CC 5

typedef __attribute__((ext_vector_type(8))) short short8;
typedef __attribute__((ext_vector_type(4))) float f32x4;

struct U4 { unsigned x, y, z, w; };
__device__ __forceinline__ short8 toB(unsigned a, unsigned b, unsigned c, unsigned d) {
    U4 u{a, b, c, d};
    return __builtin_bit_cast(short8, u);
}

__device__ __forceinline__ float fast_tanh(float x) {
    float e = __expf(2.0f * x);
    return 1.0f - 2.0f * __builtin_amdgcn_rcpf(e + 1.0f);
}
__device__ __forceinline__ unsigned short bfbits(float f) {
    __hip_bfloat16 h = __float2bfloat16(f);
    union { __hip_bfloat16 h; unsigned short u; } cv;
    cv.h = h;
    return cv.u;
}
__device__ __forceinline__ unsigned packbf(float a, float b) {
    return ((unsigned)bfbits(b) << 16) | (unsigned)bfbits(a);
}

__device__ __forceinline__ void uswap16(unsigned& u, unsigned& v) {
#if __has_builtin(__builtin_amdgcn_permlane16_swap)
    auto r = __builtin_amdgcn_permlane16_swap(u, v, false, false);
    u = r[0]; v = r[1];
#else
    asm("s_nop 1\n\tv_permlane16_swap_b32 %0, %1\n\ts_nop 0" : "+v"(u), "+v"(v));
#endif
}
__device__ __forceinline__ void uswap32(unsigned& u, unsigned& v) {
#if __has_builtin(__builtin_amdgcn_permlane32_swap)
    auto r = __builtin_amdgcn_permlane32_swap(u, v, false, false);
    u = r[0]; v = r[1];
#else
    asm("s_nop 1\n\tv_permlane32_swap_b32 %0, %1\n\ts_nop 0" : "+v"(u), "+v"(v));
#endif
}
__device__ __forceinline__ void fswap16(float& u, float& v) {
    unsigned a = __float_as_uint(u), b = __float_as_uint(v);
    uswap16(a, b);
    u = __uint_as_float(a); v = __uint_as_float(b);
}
__device__ __forceinline__ void fswap32(float& u, float& v) {
    unsigned a = __float_as_uint(u), b = __float_as_uint(v);
    uswap32(a, b);
    u = __uint_as_float(a); v = __uint_as_float(b);
}

// Broadcast the 5 packed row-dwords of one h-vector (rows 01,23,45,67,89) from
// their home lane-groups to ALL lanes. a = pack(rows 4g,4g+1), b = pack(4g+2,4g+3).
struct BC { unsigned a0, a1, a2, b0, b1; };  // a0=r01, b0=r23, a1=r45, b1=r67, a2=r89
__device__ __forceinline__ BC broadcast5(unsigned a, unsigned bq, bool f16lo, bool f32lo) {
    BC r;
    unsigned u, v;
    u = a; v = a; uswap16(u, v);
    unsigned alo = f16lo ? u : v, ahi = f16lo ? v : u;
    u = alo; v = alo; uswap32(u, v);
    r.a0 = f32lo ? u : v;
    r.a2 = f32lo ? v : u;
    u = ahi; v = ahi; uswap32(u, v);
    r.a1 = f32lo ? u : v;
    u = bq; v = bq; uswap16(u, v);
    unsigned blo = f16lo ? u : v, bhi = f16lo ? v : u;
    u = blo; v = blo; uswap32(u, v);
    r.b0 = f32lo ? u : v;
    u = bhi; v = bhi; uswap32(u, v);
    r.b1 = f32lo ? u : v;
    return r;
}

// K1: P[t][j][b] = sum_i x[b][t][i] * Wih0[j][i] + (bih0[j]+bhh0[j])
__global__ __launch_bounds__(256) void k_proj0(
    const float* __restrict__ x, const float* __restrict__ Wih0,
    const float* __restrict__ bih0, const float* __restrict__ bhh0,
    float* __restrict__ P) {
    int gid = blockIdx.x * 256 + threadIdx.x;
    int b = gid & (BB - 1);
    int t = gid >> 13;
    const float2* xr = (const float2*)(x + ((size_t)b * TT + t) * II);
    float2 xv[II / 2];
#pragma unroll
    for (int i = 0; i < II / 2; i++) xv[i] = xr[i];
#pragma unroll
    for (int j = 0; j < HH; j++) {
        float a = bih0[j] + bhh0[j];
        const float2* w = (const float2*)(Wih0 + j * II);
#pragma unroll
        for (int i = 0; i < II / 2; i++) {
            float2 wv = w[i];
            a = fmaf(wv.x, xv[i].x, a);
            a = fmaf(wv.y, xv[i].y, a);
        }
        P[((size_t)t * HH + j) * BB + b] = a;
    }
}

// K2: fused 3-layer recurrence + FC via MFMA, layer-pipelined (ILP=3).
// Iteration i runs L0@time i, L1@time i-1, L2@time i-2 — mutually independent.
// 52 iterations total; first/last have dead (finite) sub-chains that never
// merge into live state (init selects at i<=1; outputs past TT discarded).
__global__ __launch_bounds__(64, 1) void k_fused(
    const float* __restrict__ h0all,
    const float* __restrict__ Whh0,
    const float* __restrict__ Wih1, const float* __restrict__ Whh1,
    const float* __restrict__ bih1, const float* __restrict__ bhh1,
    const float* __restrict__ Wih2, const float* __restrict__ Whh2,
    const float* __restrict__ bih2, const float* __restrict__ bhh2,
    const float* __restrict__ fcw, const float* __restrict__ fcb,
    const float* __restrict__ P, float* __restrict__ out) {
    __shared__ __align__(16) float sfc[TT * CC * 16];  // fcw packed by j-row, 16 KB

    const int lane = threadIdx.x;
    const int bl = lane & 15;
    const int g = lane >> 4;
    const int b = blockIdx.x * 16 + bl;

    for (int i = lane; i < TT * CC * 16; i += 64) {
        int jj = i & 15;
        int rc = i >> 4;
        int c = rc % CC;
        int t = rc / CC;
        sfc[i] = (jj < HH) ? fcw[(size_t)c * (TT * HH) + t * HH + jj] : 0.0f;
    }

    // ---- orientation probes ----
    unsigned pu, pv;
    pu = pv = (unsigned)g; uswap16(pu, pv);
    const bool f16lo = (pu == (unsigned)(g & ~1));
    pu = pv = (unsigned)g; uswap32(pu, pv);
    const bool f32lo = (pu == (unsigned)(g & ~2));

    const bool g0 = (g == 0), g1 = (g == 1), g2 = (g == 2);

    // ---- A fragments (row m = bl, k = g*8+e) — layout verified rounds 5/6 ----
    short8 A0, A1, A2;
    const int m = bl;
#pragma unroll
    for (int e = 0; e < 8; e++) {
        int kv = g * 8 + e;
        float v0 = 0.0f, v1 = 0.0f, v2 = 0.0f;
        if (m < HH) {
            if (kv < HH) {
                v0 = Whh0[m * HH + kv];
                v1 = Wih1[m * HH + kv];
                v2 = Wih2[m * HH + kv];
            } else if (kv >= 12 && kv < 12 + HH) {
                v1 = Whh1[m * HH + (kv - 12)];
                v2 = Whh2[m * HH + (kv - 12)];
            }
        }
        A0[e] = (short)bfbits(v0);
        A1[e] = (short)bfbits(v1);
        A2[e] = (short)bfbits(v2);
    }
    f32x4 bC1, bC2;
#pragma unroll
    for (int r = 0; r < 4; r++) {
        int j = g * 4 + r;
        bC1[r] = (j < HH) ? (bih1[j] + bhh1[j]) : 0.0f;
        bC2[r] = (j < HH) ? (bih2[j] + bhh2[j]) : 0.0f;
    }

    // ---- initial state ----
    unsigned i1a0, i1b0, i1a1, i1b1, i1a2;   // h1 init (rows 01,23,45,67,89)
    unsigned i2a0, i2b0, i2a1, i2b1, i2a2;   // h2 init
    short8 B0, B1, B2;
    {
        const float* s0 = h0all + (size_t)b * HH;
        const float* s1 = h0all + ((size_t)BB + b) * HH;
        const float* s2 = h0all + ((size_t)2 * BB + b) * HH;
        unsigned h0p[5];
#pragma unroll
        for (int r = 0; r < 5; r++) h0p[r] = packbf(s0[2 * r], s0[2 * r + 1]);
        i1a0 = packbf(s1[0], s1[1]); i1b0 = packbf(s1[2], s1[3]);
        i1a1 = packbf(s1[4], s1[5]); i1b1 = packbf(s1[6], s1[7]);
        i1a2 = packbf(s1[8], s1[9]);
        i2a0 = packbf(s2[0], s2[1]); i2b0 = packbf(s2[2], s2[3]);
        i2a1 = packbf(s2[4], s2[5]); i2b1 = packbf(s2[6], s2[7]);
        i2a2 = packbf(s2[8], s2[9]);
        B0 = toB(g0 ? h0p[0] : (g1 ? h0p[4] : 0u),
                 g0 ? h0p[1] : 0u,
                 g0 ? h0p[2] : 0u,
                 g0 ? h0p[3] : 0u);
        B1 = toB(0u, 0u, 0u, 0u);   // L1@-1: dead chain, finite
        B2 = toB(0u, 0u, 0u, 0u);   // L2@-2: dead chain, finite
    }

    float acc[CC] = {0.0f, 0.0f, 0.0f, 0.0f, 0.0f};

    f32x4 pcur;
#pragma unroll
    for (int r = 0; r < 4; r++) {
        int j = g * 4 + r;
        pcur[r] = (j < HH) ? P[((size_t)0 * HH + j) * BB + b] : 0.0f;
    }

#pragma unroll 1
    for (int i = 0; i < TT + 2; i++) {
        // FC weights for time tau = i-2 (clamped; gated below)
        int tauc = (i >= 2) ? (i - 2) : 0;
        f32x4 fcv[CC];
#pragma unroll
        for (int c = 0; c < CC; c++)
            fcv[c] = *(const f32x4*)&sfc[(tauc * CC + c) * 16 + g * 4];
        // prefetch P for time i+1 (clamped)
        int tp = (i + 1 < TT) ? (i + 1) : (TT - 1);
        f32x4 pn;
#pragma unroll
        for (int r = 0; r < 4; r++) {
            int j = g * 4 + r;
            pn[r] = (j < HH) ? P[((size_t)tp * HH + j) * BB + b] : 0.0f;
        }

        // ---- three independent MFMAs (staggered timesteps) ----
        f32x4 D0 = __builtin_amdgcn_mfma_f32_16x16x32_bf16(A0, B0, pcur, 0, 0, 0);
        f32x4 D1 = __builtin_amdgcn_mfma_f32_16x16x32_bf16(A1, B1, bC1, 0, 0, 0);
        f32x4 D2 = __builtin_amdgcn_mfma_f32_16x16x32_bf16(A2, B2, bC2, 0, 0, 0);

        float th0[4], th1[4], th2[4];
#pragma unroll
        for (int r = 0; r < 4; r++) th0[r] = fast_tanh(D0[r]);
#pragma unroll
        for (int r = 0; r < 4; r++) th1[r] = fast_tanh(D1[r]);
#pragma unroll
        for (int r = 0; r < 4; r++) th2[r] = fast_tanh(D2[r]);

        BC bc0 = broadcast5(packbf(th0[0], th0[1]), packbf(th0[2], th0[3]), f16lo, f32lo);
        BC bc1 = broadcast5(packbf(th1[0], th1[1]), packbf(th1[2], th1[3]), f16lo, f32lo);
        BC bc2 = broadcast5(packbf(th2[0], th2[1]), packbf(th2[2], th2[3]), f16lo, f32lo);

        // ---- FC accumulate for time i-2 (live only when i>=2) ----
        if (i >= 2) {
#pragma unroll
            for (int c = 0; c < CC; c++) {
#pragma unroll
                for (int r = 0; r < 4; r++)
                    acc[c] = fmaf(fcv[c][r], fmaxf(th2[r], 0.0f), acc[c]);
            }
        }

        // ---- init-state overrides for pipeline fill ----
        unsigned s1a0 = (i == 0) ? i1a0 : bc1.a0;
        unsigned s1b0 = (i == 0) ? i1b0 : bc1.b0;
        unsigned s1a1 = (i == 0) ? i1a1 : bc1.a1;
        unsigned s1b1 = (i == 0) ? i1b1 : bc1.b1;
        unsigned s1a2 = (i == 0) ? i1a2 : bc1.a2;
        unsigned s2a0 = (i <= 1) ? i2a0 : bc2.a0;
        unsigned s2b0 = (i <= 1) ? i2b0 : bc2.b0;
        unsigned s2a1 = (i <= 1) ? i2a1 : bc2.a1;
        unsigned s2b1 = (i <= 1) ? i2b1 : bc2.b1;
        unsigned s2a2 = (i <= 1) ? i2a2 : bc2.a2;

        // ---- assemble next-iteration operands ----
        // B0: L0@i+1 needs h0(i)=bc0 at k0-9
        B0 = toB(g0 ? bc0.a0 : (g1 ? bc0.a2 : 0u),
                 g0 ? bc0.b0 : 0u,
                 g0 ? bc0.a1 : 0u,
                 g0 ? bc0.b1 : 0u);
        // B1: L1@i needs h0(i)=bc0 at k0-9, h1(i-1)=s1 at k12-21
        B1 = toB(g0 ? bc0.a0 : (g1 ? bc0.a2 : (g2 ? s1a1 : 0u)),
                 g0 ? bc0.b0 : (g2 ? s1b1 : 0u),
                 g0 ? bc0.a1 : (g1 ? s1a0 : (g2 ? s1a2 : 0u)),
                 g0 ? bc0.b1 : (g1 ? s1b0 : 0u));
        // B2: L2@i-1 needs h1(i-1)=s1(=bc1 for i>=1) at k0-9, h2(i-2)=s2 at k12-21
        B2 = toB(g0 ? s1a0 : (g1 ? s1a2 : (g2 ? s2a1 : 0u)),
                 g0 ? s1b0 : (g2 ? s2b1 : 0u),
                 g0 ? s1a1 : (g1 ? s2a0 : (g2 ? s2a2 : 0u)),
                 g0 ? s1b1 : (g1 ? s2b0 : 0u));

        pcur = pn;
    }

    // reduce acc across the 4 lane groups (commutative sums, orientation-immune)
#pragma unroll
    for (int c = 0; c < CC; c++) {
        float u = acc[c], v = acc[c];
        fswap16(u, v);
        float s = u + v;
        float u2 = s, v2 = s;
        fswap32(u2, v2);
        acc[c] = u2 + v2 + fcb[c];
    }
    if (g == 0) {
#pragma unroll
        for (int c = 0; c < CC; c++) out[(size_t)b * CC + c] = acc[c];
    }
}

extern "C" void kernel_launch(void* const* d_in, const int* in_sizes, int n_in,
                              void* d_out, int out_size, void* d_ws, size_t ws_size,
                              hipStream_t stream) {
    const float* x    = (const float*)d_in[0];
    const float* h0   = (const float*)d_in[1];
    const float* Wih0 = (const float*)d_in[2];
    const float* Whh0 = (const float*)d_in[3];
    const float* bih0 = (const float*)d_in[4];
    const float* bhh0 = (const float*)d_in[5];
    const float* Wih1 = (const float*)d_in[6];
    const float* Whh1 = (const float*)d_in[7];
    const float* bih1 = (const float*)d_in[8];
    const float* bhh1 = (const float*)d_in[9];
    const float* Wih2 = (const float*)d_in[10];
    const float* Whh2 = (const float*)d_in[11];
    const float* bih2 = (const float*)d_in[12];
    const float* bhh2 = (const float*)d_in[13];
    const float* fcw  = (const float*)d_in[14];
    const float* fcb  = (const float*)d_in[15];
    float* out = (float*)d_out;
    float* P   = (float*)d_ws;   // [T][H][B] = 16.38 MB

    k_proj0<<<(BB * TT) / 256, 256, 0, stream>>>(x, Wih0, bih0, bhh0, P);
    k_fused<<<BB / 16, 64, 0, stream>>>(h0, Whh0, Wih1, Whh1, bih1, bhh1,
                                        Wih2, Whh2, bih2, bhh2, fcw, fcb, P, out);
}